// Round 1
// baseline (2186.230 us; speedup 1.0000x reference)
//
#include <hip/hip_runtime.h>
#include <math.h>

#define NN 50000
#define NE 640000
#define F  128

// ---------------- degree: deg[c] += 1 per edge ----------------
__global__ __launch_bounds__(256) void deg_kernel(const int* __restrict__ col,
                                                  float* __restrict__ deg) {
    int e = blockIdx.x * 256 + threadIdx.x;
    if (e < NE) atomicAdd(&deg[col[e]], 1.0f);
}

// ---------------- dinv[i] = deg>0 ? deg^-0.5 : 0 ----------------
__global__ __launch_bounds__(256) void dinv_kernel(const float* __restrict__ deg,
                                                   float* __restrict__ dinv) {
    int i = blockIdx.x * 256 + threadIdx.x;
    if (i < NN) {
        float d = deg[i];
        dinv[i] = (d > 0.0f) ? (1.0f / sqrtf(d)) : 0.0f;
    }
}

// ---------------- edge scatter: 32 threads per edge, 4 feats each ----------------
__global__ __launch_bounds__(256) void scatter_kernel(
        const int* __restrict__ row, const int* __restrict__ col,
        const float* __restrict__ x, const float* __restrict__ mask,
        const float* __restrict__ dinv,
        float* __restrict__ num, float* __restrict__ den,
        float* __restrict__ rowsum) {
    int t = blockIdx.x * 256 + threadIdx.x;
    int e = t >> 5;
    if (e >= NE) return;
    int lane = t & 31;
    int r = row[e];
    int c = col[e];
    float w = dinv[r] * dinv[c];
    if (lane == 0) atomicAdd(&rowsum[r], w);

    int f = lane * 4;
    size_t cbase = (size_t)c * F + f;
    size_t rbase = (size_t)r * F + f;
    float4 xv = *(const float4*)(x + cbase);
    float4 mv = *(const float4*)(mask + cbase);
    // nan_to_num(x)
    float x0 = (xv.x != xv.x) ? 0.0f : xv.x;
    float x1 = (xv.y != xv.y) ? 0.0f : xv.y;
    float x2 = (xv.z != xv.z) ? 0.0f : xv.z;
    float x3 = (xv.w != xv.w) ? 0.0f : xv.w;
    // mask is 0/1: skip atomics where mask==0 (halves atomic traffic)
    if (mv.x != 0.0f) { atomicAdd(num + rbase + 0, w * mv.x * x0); atomicAdd(den + rbase + 0, w * mv.x); }
    if (mv.y != 0.0f) { atomicAdd(num + rbase + 1, w * mv.y * x1); atomicAdd(den + rbase + 1, w * mv.y); }
    if (mv.z != 0.0f) { atomicAdd(num + rbase + 2, w * mv.z * x2); atomicAdd(den + rbase + 2, w * mv.z); }
    if (mv.w != 0.0f) { atomicAdd(num + rbase + 3, w * mv.w * x3); atomicAdd(den + rbase + 3, w * mv.w); }
}

// ---------------- ratio = den!=0 ? rowsum*num/den : 0  (in-place into den) ----------------
__global__ __launch_bounds__(256) void ratio_kernel(const float* __restrict__ num,
                                                    float* __restrict__ den,
                                                    const float* __restrict__ rowsum) {
    int i = blockIdx.x * 256 + threadIdx.x;   // NN*F == 25000*256 exactly
    float d = den[i];
    float out = 0.0f;
    if (d != 0.0f) out = rowsum[i >> 7] * num[i] / d;
    den[i] = out;
}

// ---------------- out = ratio @ W^T + b ----------------
__global__ __launch_bounds__(256) void gemm_kernel(const float* __restrict__ A,
                                                   const float* __restrict__ W,
                                                   const float* __restrict__ bias,
                                                   float* __restrict__ out) {
    __shared__ float As[32][F];    // 16 KB
    __shared__ float Wt[F][F];     // 64 KB, Wt[k][c] = W[c][k]
    int tid = threadIdx.x;
    int row0 = blockIdx.x * 32;

    for (int i = tid * 4; i < 32 * F; i += 256 * 4) {
        int r = i >> 7, k = i & 127;
        int gr = row0 + r;
        float4 v = make_float4(0.f, 0.f, 0.f, 0.f);
        if (gr < NN) v = *(const float4*)(A + (size_t)gr * F + k);
        *(float4*)&As[r][k] = v;
    }
    for (int i = tid * 4; i < F * F; i += 256 * 4) {
        int cc = i >> 7, k = i & 127;
        float4 v = *(const float4*)(W + cc * F + k);
        Wt[k + 0][cc] = v.x;
        Wt[k + 1][cc] = v.y;
        Wt[k + 2][cc] = v.z;
        Wt[k + 3][cc] = v.w;
    }
    __syncthreads();

    int tidr = tid >> 5, tidc = tid & 31;
    int r0 = tidr * 4, c0 = tidc * 4;
    float acc[4][4] = {};
    for (int k = 0; k < F; ++k) {
        float a0 = As[r0 + 0][k];
        float a1 = As[r0 + 1][k];
        float a2 = As[r0 + 2][k];
        float a3 = As[r0 + 3][k];
        float4 wv = *(float4*)&Wt[k][c0];
        acc[0][0] += a0 * wv.x; acc[0][1] += a0 * wv.y; acc[0][2] += a0 * wv.z; acc[0][3] += a0 * wv.w;
        acc[1][0] += a1 * wv.x; acc[1][1] += a1 * wv.y; acc[1][2] += a1 * wv.z; acc[1][3] += a1 * wv.w;
        acc[2][0] += a2 * wv.x; acc[2][1] += a2 * wv.y; acc[2][2] += a2 * wv.z; acc[2][3] += a2 * wv.w;
        acc[3][0] += a3 * wv.x; acc[3][1] += a3 * wv.y; acc[3][2] += a3 * wv.z; acc[3][3] += a3 * wv.w;
    }
    float4 bv = *(const float4*)(bias + c0);
    for (int ii = 0; ii < 4; ++ii) {
        int gr = row0 + r0 + ii;
        if (gr < NN) {
            float4 o = make_float4(acc[ii][0] + bv.x, acc[ii][1] + bv.y,
                                   acc[ii][2] + bv.z, acc[ii][3] + bv.w);
            *(float4*)(out + (size_t)gr * F + c0) = o;
        }
    }
}

extern "C" void kernel_launch(void* const* d_in, const int* in_sizes, int n_in,
                              void* d_out, int out_size, void* d_ws, size_t ws_size,
                              hipStream_t stream) {
    const float* x    = (const float*)d_in[0];
    const float* mask = (const float*)d_in[1];
    const int*   ei   = (const int*)d_in[2];   // [2, E] row-major: row then col
    const float* W    = (const float*)d_in[3];
    const float* b    = (const float*)d_in[4];
    float* out = (float*)d_out;

    // workspace layout: den [NN*F] | deg [NN] | rowsum [NN] | dinv [NN]
    float* den    = (float*)d_ws;
    float* deg    = den + (size_t)NN * F;
    float* rowsum = deg + NN;
    float* dinv   = rowsum + NN;

    const int* row = ei;
    const int* col = ei + NE;

    // zero: numerator accumulator (d_out), den, deg, rowsum (contiguous)
    hipMemsetAsync(out, 0, (size_t)NN * F * sizeof(float), stream);
    hipMemsetAsync(den, 0, ((size_t)NN * F + 2 * NN) * sizeof(float), stream);

    deg_kernel<<<(NE + 255) / 256, 256, 0, stream>>>(col, deg);
    dinv_kernel<<<(NN + 255) / 256, 256, 0, stream>>>(deg, dinv);
    scatter_kernel<<<(NE * 32) / 256, 256, 0, stream>>>(row, col, x, mask, dinv,
                                                        out, den, rowsum);
    ratio_kernel<<<(NN * F) / 256, 256, 0, stream>>>(out, den, rowsum);
    gemm_kernel<<<(NN + 31) / 32, 256, 0, stream>>>(den, W, b, out);
}

// Round 2
// 395.848 us; speedup vs baseline: 5.5229x; 5.5229x over previous
//
#include <hip/hip_runtime.h>
#include <math.h>

#define NN 50000
#define NE 640000
#define F  128

// ---- histogram: cnt_col[c]++ (for normalization), cnt_row[r]++ (for CSR) ----
__global__ __launch_bounds__(256) void hist_kernel(const int* __restrict__ row,
                                                   const int* __restrict__ col,
                                                   int* __restrict__ cnt_row,
                                                   int* __restrict__ cnt_col) {
    int e = blockIdx.x * 256 + threadIdx.x;
    if (e < NE) {
        atomicAdd(&cnt_row[row[e]], 1);
        atomicAdd(&cnt_col[col[e]], 1);
    }
}

// ---- dinv[i] = cnt_col>0 ? cnt_col^-0.5 : 0 ----
__global__ __launch_bounds__(256) void dinv_kernel(const int* __restrict__ cnt_col,
                                                   float* __restrict__ dinv) {
    int i = blockIdx.x * 256 + threadIdx.x;
    if (i < NN) {
        int d = cnt_col[i];
        dinv[i] = (d > 0) ? rsqrtf((float)d) : 0.0f;
    }
}

// ---- exclusive scan of cnt_row -> rowstart[NN+1], also fill cursor ----
__global__ __launch_bounds__(1024) void scan_kernel(const int* __restrict__ cnt,
                                                    int* __restrict__ rowstart,
                                                    int* __restrict__ cursor) {
    __shared__ int wsum[16];
    __shared__ int carry_s;
    int tid = threadIdx.x;
    int lane = tid & 63, wid = tid >> 6;
    if (tid == 0) carry_s = 0;
    __syncthreads();
    for (int base = 0; base < NN; base += 1024) {
        int i = base + tid;
        int v = (i < NN) ? cnt[i] : 0;
        // wave inclusive scan
        int incl = v;
        #pragma unroll
        for (int off = 1; off < 64; off <<= 1) {
            int t = __shfl_up(incl, off);
            if (lane >= off) incl += t;
        }
        if (lane == 63) wsum[wid] = incl;
        __syncthreads();
        if (wid == 0) {
            int s = (lane < 16) ? wsum[lane] : 0;
            #pragma unroll
            for (int off = 1; off < 16; off <<= 1) {
                int t = __shfl_up(s, off);
                if (lane >= off) s += t;
            }
            if (lane < 16) wsum[lane] = s;
        }
        __syncthreads();
        int carry = carry_s;
        int wbase = (wid > 0) ? wsum[wid - 1] : 0;
        int excl = carry + wbase + incl - v;
        if (i < NN) { rowstart[i] = excl; cursor[i] = excl; }
        __syncthreads();
        if (tid == 0) carry_s = carry + wsum[15];
        __syncthreads();
    }
    if (tid == 0) rowstart[NN] = carry_s;
}

// ---- counting-sort scatter: srcs[pos++] = col[e], bucketed by row[e] ----
__global__ __launch_bounds__(256) void sort_kernel(const int* __restrict__ row,
                                                   const int* __restrict__ col,
                                                   int* __restrict__ cursor,
                                                   int* __restrict__ srcs) {
    int e = blockIdx.x * 256 + threadIdx.x;
    if (e < NE) {
        int p = atomicAdd(&cursor[row[e]], 1);
        srcs[p] = col[e];
    }
}

// ---- gather + fused ratio: one wave per dst node, 2 feats/lane ----
// ratio[r][f] = (den>0) ? dinv_r * S * num / den : 0
//   with S = sum dinv_c, num = sum dinv_c*m*x, den = sum dinv_c*m
__global__ __launch_bounds__(256) void gather_kernel(
        const int* __restrict__ rowstart, const int* __restrict__ srcs,
        const float* __restrict__ dinv,
        const float* __restrict__ x, const float* __restrict__ mask,
        float* __restrict__ ratio) {
    int lane = threadIdx.x & 63;
    int r = blockIdx.x * 4 + (threadIdx.x >> 6);   // NN = 12500*4 exactly
    const float2* xp = (const float2*)x;
    const float2* mp = (const float2*)mask;

    int s0 = rowstart[r], s1 = rowstart[r + 1];
    float dr = dinv[r];
    float2 num = make_float2(0.f, 0.f);
    float2 den = make_float2(0.f, 0.f);
    float S = 0.f;

    int j = s0;
    for (; j + 1 < s1; j += 2) {
        int c0 = srcs[j], c1 = srcs[j + 1];
        float w0 = dinv[c0], w1 = dinv[c1];
        float2 xa = xp[(size_t)c0 * 64 + lane];
        float2 ma = mp[(size_t)c0 * 64 + lane];
        float2 xb = xp[(size_t)c1 * 64 + lane];
        float2 mb = mp[(size_t)c1 * 64 + lane];
        float xa0 = (xa.x != xa.x) ? 0.f : xa.x;
        float xa1 = (xa.y != xa.y) ? 0.f : xa.y;
        float xb0 = (xb.x != xb.x) ? 0.f : xb.x;
        float xb1 = (xb.y != xb.y) ? 0.f : xb.y;
        S += w0 + w1;
        num.x += w0 * ma.x * xa0 + w1 * mb.x * xb0;
        num.y += w0 * ma.y * xa1 + w1 * mb.y * xb1;
        den.x += w0 * ma.x + w1 * mb.x;
        den.y += w0 * ma.y + w1 * mb.y;
    }
    if (j < s1) {
        int c0 = srcs[j];
        float w0 = dinv[c0];
        float2 xa = xp[(size_t)c0 * 64 + lane];
        float2 ma = mp[(size_t)c0 * 64 + lane];
        float xa0 = (xa.x != xa.x) ? 0.f : xa.x;
        float xa1 = (xa.y != xa.y) ? 0.f : xa.y;
        S += w0;
        num.x += w0 * ma.x * xa0;
        num.y += w0 * ma.y * xa1;
        den.x += w0 * ma.x;
        den.y += w0 * ma.y;
    }

    float k = dr * S;
    float2 o;
    o.x = (den.x != 0.f) ? k * num.x / den.x : 0.f;
    o.y = (den.y != 0.f) ? k * num.y / den.y : 0.f;
    ((float2*)ratio)[(size_t)r * 64 + lane] = o;
}

// ---- out = A @ W^T + b  (safe in-place: each block reads only rows it writes) ----
__global__ __launch_bounds__(256) void gemm_kernel(const float* __restrict__ A,
                                                   const float* __restrict__ W,
                                                   const float* __restrict__ bias,
                                                   float* __restrict__ out) {
    __shared__ float As[32][F];
    __shared__ float Wt[F][F];
    int tid = threadIdx.x;
    int row0 = blockIdx.x * 32;

    for (int i = tid * 4; i < 32 * F; i += 256 * 4) {
        int r = i >> 7, k = i & 127;
        int gr = row0 + r;
        float4 v = make_float4(0.f, 0.f, 0.f, 0.f);
        if (gr < NN) v = *(const float4*)(A + (size_t)gr * F + k);
        *(float4*)&As[r][k] = v;
    }
    for (int i = tid * 4; i < F * F; i += 256 * 4) {
        int cc = i >> 7, k = i & 127;
        float4 v = *(const float4*)(W + cc * F + k);
        Wt[k + 0][cc] = v.x;
        Wt[k + 1][cc] = v.y;
        Wt[k + 2][cc] = v.z;
        Wt[k + 3][cc] = v.w;
    }
    __syncthreads();

    int tidr = tid >> 5, tidc = tid & 31;
    int r0 = tidr * 4, c0 = tidc * 4;
    float acc[4][4] = {};
    for (int k = 0; k < F; ++k) {
        float a0 = As[r0 + 0][k];
        float a1 = As[r0 + 1][k];
        float a2 = As[r0 + 2][k];
        float a3 = As[r0 + 3][k];
        float4 wv = *(float4*)&Wt[k][c0];
        acc[0][0] += a0 * wv.x; acc[0][1] += a0 * wv.y; acc[0][2] += a0 * wv.z; acc[0][3] += a0 * wv.w;
        acc[1][0] += a1 * wv.x; acc[1][1] += a1 * wv.y; acc[1][2] += a1 * wv.z; acc[1][3] += a1 * wv.w;
        acc[2][0] += a2 * wv.x; acc[2][1] += a2 * wv.y; acc[2][2] += a2 * wv.z; acc[2][3] += a2 * wv.w;
        acc[3][0] += a3 * wv.x; acc[3][1] += a3 * wv.y; acc[3][2] += a3 * wv.z; acc[3][3] += a3 * wv.w;
    }
    float4 bv = *(const float4*)(bias + c0);
    for (int ii = 0; ii < 4; ++ii) {
        int gr = row0 + r0 + ii;
        if (gr < NN) {
            float4 o = make_float4(acc[ii][0] + bv.x, acc[ii][1] + bv.y,
                                   acc[ii][2] + bv.z, acc[ii][3] + bv.w);
            *(float4*)(out + (size_t)gr * F + c0) = o;
        }
    }
}

extern "C" void kernel_launch(void* const* d_in, const int* in_sizes, int n_in,
                              void* d_out, int out_size, void* d_ws, size_t ws_size,
                              hipStream_t stream) {
    const float* x    = (const float*)d_in[0];
    const float* mask = (const float*)d_in[1];
    const int*   ei   = (const int*)d_in[2];   // [2, E]: row then col
    const float* W    = (const float*)d_in[3];
    const float* b    = (const float*)d_in[4];
    float* out = (float*)d_out;

    const int* row = ei;
    const int* col = ei + NE;

    // ws layout (ints/floats, 4 B each):
    int*   cnt_row  = (int*)d_ws;              // [NN]
    int*   cnt_col  = cnt_row + NN;            // [NN]
    int*   rowstart = cnt_col + NN;            // [NN+1]
    int*   cursor   = rowstart + NN + 1;       // [NN]
    int*   srcs     = cursor + NN;             // [NE]
    float* dinv     = (float*)(srcs + NE);     // [NN]

    hipMemsetAsync(cnt_row, 0, 2 * NN * sizeof(int), stream);

    hist_kernel<<<(NE + 255) / 256, 256, 0, stream>>>(row, col, cnt_row, cnt_col);
    dinv_kernel<<<(NN + 255) / 256, 256, 0, stream>>>(cnt_col, dinv);
    scan_kernel<<<1, 1024, 0, stream>>>(cnt_row, rowstart, cursor);
    sort_kernel<<<(NE + 255) / 256, 256, 0, stream>>>(row, col, cursor, srcs);
    gather_kernel<<<NN / 4, 256, 0, stream>>>(rowstart, srcs, dinv, x, mask, out);
    gemm_kernel<<<(NN + 31) / 32, 256, 0, stream>>>(out, W, b, out);
}

// Round 3
// 325.008 us; speedup vs baseline: 6.7267x; 1.2180x over previous
//
#include <hip/hip_runtime.h>
#include <math.h>

#define NN 50000
#define NE 640000
#define F  128
#define SCHUNK 1024
#define SNB 49   // ceil(NN/SCHUNK)

// ---- pack: mx[n][f] = bf16(mask*nan_to_num(x)), bits[n] = 128-bit mask ----
__global__ __launch_bounds__(256) void pack_kernel(const float* __restrict__ x,
                                                   const float* __restrict__ mask,
                                                   unsigned* __restrict__ mx,
                                                   unsigned long long* __restrict__ bits) {
    int lane = threadIdx.x & 63;
    int n = blockIdx.x * 4 + (threadIdx.x >> 6);   // NN = 12500*4
    float2 xv = ((const float2*)x)[(size_t)n * 64 + lane];
    float2 mv = ((const float2*)mask)[(size_t)n * 64 + lane];
    float x0 = (xv.x != xv.x) ? 0.f : xv.x;
    float x1 = (xv.y != xv.y) ? 0.f : xv.y;
    float p0 = (mv.x != 0.f) ? x0 : 0.f;
    float p1 = (mv.y != 0.f) ? x1 : 0.f;
    unsigned u0 = __float_as_uint(p0), u1 = __float_as_uint(p1);
    u0 = (u0 + 0x7fffu + ((u0 >> 16) & 1u)) >> 16;   // RNE to bf16
    u1 = (u1 + 0x7fffu + ((u1 >> 16) & 1u)) >> 16;
    mx[(size_t)n * 64 + lane] = (u1 << 16) | u0;
    unsigned long long b0 = __ballot(mv.x != 0.f);   // bit l = mask[2l]
    unsigned long long b1 = __ballot(mv.y != 0.f);   // bit l = mask[2l+1]
    if (lane == 0) {
        bits[2 * (size_t)n]     = b0;
        bits[2 * (size_t)n + 1] = b1;
    }
}

// ---- histogram ----
__global__ __launch_bounds__(256) void hist_kernel(const int* __restrict__ row,
                                                   const int* __restrict__ col,
                                                   int* __restrict__ cnt_row,
                                                   int* __restrict__ cnt_col) {
    int e = blockIdx.x * 256 + threadIdx.x;
    if (e < NE) {
        atomicAdd(&cnt_row[row[e]], 1);
        atomicAdd(&cnt_col[col[e]], 1);
    }
}

__global__ __launch_bounds__(256) void dinv_kernel(const int* __restrict__ cnt_col,
                                                   float* __restrict__ dinv) {
    int i = blockIdx.x * 256 + threadIdx.x;
    if (i < NN) {
        int d = cnt_col[i];
        dinv[i] = (d > 0) ? rsqrtf((float)d) : 0.0f;
    }
}

// ---- 3-phase parallel exclusive scan of cnt_row ----
__global__ __launch_bounds__(256) void scan_a(const int* __restrict__ cnt,
                                              int* __restrict__ bsum) {
    int base = blockIdx.x * SCHUNK + threadIdx.x * 4;
    int s = 0;
    #pragma unroll
    for (int k = 0; k < 4; k++) { int i = base + k; if (i < NN) s += cnt[i]; }
    #pragma unroll
    for (int off = 32; off; off >>= 1) s += __shfl_down(s, off);
    __shared__ int ws[4];
    int lane = threadIdx.x & 63, wid = threadIdx.x >> 6;
    if (lane == 0) ws[wid] = s;
    __syncthreads();
    if (threadIdx.x == 0) bsum[blockIdx.x] = ws[0] + ws[1] + ws[2] + ws[3];
}

__global__ void scan_b(const int* __restrict__ bsum, int* __restrict__ boffset,
                       int* __restrict__ rowstart) {
    int l = threadIdx.x;
    int v = (l < SNB) ? bsum[l] : 0;
    int incl = v;
    #pragma unroll
    for (int off = 1; off < 64; off <<= 1) {
        int t = __shfl_up(incl, off);
        if (l >= off) incl += t;
    }
    if (l < SNB) boffset[l] = incl - v;
    if (l == 63) rowstart[NN] = incl;
}

__global__ __launch_bounds__(256) void scan_c(const int* __restrict__ cnt,
                                              const int* __restrict__ boffset,
                                              int* __restrict__ rowstart,
                                              int* __restrict__ cursor) {
    int base = blockIdx.x * SCHUNK + threadIdx.x * 4;
    int v[4]; int ts = 0;
    #pragma unroll
    for (int k = 0; k < 4; k++) { int i = base + k; v[k] = (i < NN) ? cnt[i] : 0; ts += v[k]; }
    int lane = threadIdx.x & 63, wid = threadIdx.x >> 6;
    int incl = ts;
    #pragma unroll
    for (int off = 1; off < 64; off <<= 1) {
        int t = __shfl_up(incl, off);
        if (lane >= off) incl += t;
    }
    __shared__ int ws[4];
    if (lane == 63) ws[wid] = incl;
    __syncthreads();
    int wbase = 0;
    for (int k = 0; k < wid; k++) wbase += ws[k];
    int run = boffset[blockIdx.x] + wbase + incl - ts;
    #pragma unroll
    for (int k = 0; k < 4; k++) {
        int i = base + k;
        if (i < NN) { rowstart[i] = run; cursor[i] = run; }
        run += v[k];
    }
}

// ---- counting-sort scatter ----
__global__ __launch_bounds__(256) void sort_kernel(const int* __restrict__ row,
                                                   const int* __restrict__ col,
                                                   int* __restrict__ cursor,
                                                   int* __restrict__ srcs) {
    int e = blockIdx.x * 256 + threadIdx.x;
    if (e < NE) {
        int p = atomicAdd(&cursor[row[e]], 1);
        srcs[p] = col[e];
    }
}

// ---- gather + fused ratio: one wave per dst node, bf16 mx + bitmask den ----
__global__ __launch_bounds__(256) void gather_kernel(
        const int* __restrict__ rowstart, const int* __restrict__ srcs,
        const float* __restrict__ dinv,
        const unsigned* __restrict__ mx, const unsigned long long* __restrict__ bits,
        float* __restrict__ ratio) {
    int lane = threadIdx.x & 63;
    int r = blockIdx.x * 4 + (threadIdx.x >> 6);
    int s0 = rowstart[r], s1 = rowstart[r + 1];
    float dr = dinv[r];
    float n0 = 0.f, n1 = 0.f, d0 = 0.f, d1 = 0.f, S = 0.f;

    int j = s0;
    for (; j + 1 < s1; j += 2) {
        int ca = srcs[j], cb = srcs[j + 1];
        float wa = dinv[ca], wb = dinv[cb];
        unsigned ua = mx[(size_t)ca * 64 + lane];
        unsigned ub = mx[(size_t)cb * 64 + lane];
        ulonglong2 ba = ((const ulonglong2*)bits)[ca];
        ulonglong2 bb = ((const ulonglong2*)bits)[cb];
        float fa0 = __uint_as_float(ua << 16);
        float fa1 = __uint_as_float(ua & 0xffff0000u);
        float fb0 = __uint_as_float(ub << 16);
        float fb1 = __uint_as_float(ub & 0xffff0000u);
        S += wa + wb;
        n0 += wa * fa0 + wb * fb0;
        n1 += wa * fa1 + wb * fb1;
        d0 += (((ba.x >> lane) & 1ull) ? wa : 0.f) + (((bb.x >> lane) & 1ull) ? wb : 0.f);
        d1 += (((ba.y >> lane) & 1ull) ? wa : 0.f) + (((bb.y >> lane) & 1ull) ? wb : 0.f);
    }
    if (j < s1) {
        int ca = srcs[j];
        float wa = dinv[ca];
        unsigned ua = mx[(size_t)ca * 64 + lane];
        ulonglong2 ba = ((const ulonglong2*)bits)[ca];
        float fa0 = __uint_as_float(ua << 16);
        float fa1 = __uint_as_float(ua & 0xffff0000u);
        S += wa;
        n0 += wa * fa0;
        n1 += wa * fa1;
        d0 += ((ba.x >> lane) & 1ull) ? wa : 0.f;
        d1 += ((ba.y >> lane) & 1ull) ? wa : 0.f;
    }

    float k = dr * S;
    float2 o;
    o.x = (d0 != 0.f) ? k * n0 / d0 : 0.f;
    o.y = (d1 != 0.f) ? k * n1 / d1 : 0.f;
    ((float2*)ratio)[(size_t)r * 64 + lane] = o;
}

// ---- out = A @ W^T + b  (in-place safe per 32-row tile) ----
__global__ __launch_bounds__(256) void gemm_kernel(const float* __restrict__ A,
                                                   const float* __restrict__ W,
                                                   const float* __restrict__ bias,
                                                   float* __restrict__ out) {
    __shared__ float As[32][F];
    __shared__ float Wt[F][F];
    int tid = threadIdx.x;
    int row0 = blockIdx.x * 32;

    for (int i = tid * 4; i < 32 * F; i += 256 * 4) {
        int r = i >> 7, k = i & 127;
        int gr = row0 + r;
        float4 v = make_float4(0.f, 0.f, 0.f, 0.f);
        if (gr < NN) v = *(const float4*)(A + (size_t)gr * F + k);
        *(float4*)&As[r][k] = v;
    }
    for (int i = tid * 4; i < F * F; i += 256 * 4) {
        int cc = i >> 7, k = i & 127;
        float4 v = *(const float4*)(W + cc * F + k);
        Wt[k + 0][cc] = v.x;
        Wt[k + 1][cc] = v.y;
        Wt[k + 2][cc] = v.z;
        Wt[k + 3][cc] = v.w;
    }
    __syncthreads();

    int tidr = tid >> 5, tidc = tid & 31;
    int r0 = tidr * 4, c0 = tidc * 4;
    float acc[4][4] = {};
    for (int k = 0; k < F; ++k) {
        float a0 = As[r0 + 0][k];
        float a1 = As[r0 + 1][k];
        float a2 = As[r0 + 2][k];
        float a3 = As[r0 + 3][k];
        float4 wv = *(float4*)&Wt[k][c0];
        acc[0][0] += a0 * wv.x; acc[0][1] += a0 * wv.y; acc[0][2] += a0 * wv.z; acc[0][3] += a0 * wv.w;
        acc[1][0] += a1 * wv.x; acc[1][1] += a1 * wv.y; acc[1][2] += a1 * wv.z; acc[1][3] += a1 * wv.w;
        acc[2][0] += a2 * wv.x; acc[2][1] += a2 * wv.y; acc[2][2] += a2 * wv.z; acc[2][3] += a2 * wv.w;
        acc[3][0] += a3 * wv.x; acc[3][1] += a3 * wv.y; acc[3][2] += a3 * wv.z; acc[3][3] += a3 * wv.w;
    }
    float4 bv = *(const float4*)(bias + c0);
    for (int ii = 0; ii < 4; ++ii) {
        int gr = row0 + r0 + ii;
        if (gr < NN) {
            float4 o = make_float4(acc[ii][0] + bv.x, acc[ii][1] + bv.y,
                                   acc[ii][2] + bv.z, acc[ii][3] + bv.w);
            *(float4*)(out + (size_t)gr * F + c0) = o;
        }
    }
}

extern "C" void kernel_launch(void* const* d_in, const int* in_sizes, int n_in,
                              void* d_out, int out_size, void* d_ws, size_t ws_size,
                              hipStream_t stream) {
    const float* x    = (const float*)d_in[0];
    const float* mask = (const float*)d_in[1];
    const int*   ei   = (const int*)d_in[2];
    const float* W    = (const float*)d_in[3];
    const float* b    = (const float*)d_in[4];
    float* out = (float*)d_out;

    const int* row = ei;
    const int* col = ei + NE;

    // ws layout
    unsigned*           mx       = (unsigned*)d_ws;                     // NN*64 (12.8 MB)
    unsigned long long* bits     = (unsigned long long*)(mx + (size_t)NN * 64); // NN*2 (16B-aligned)
    int*                srcs     = (int*)(bits + (size_t)NN * 2);       // NE
    int*                cnt_row  = srcs + NE;                           // NN
    int*                cnt_col  = cnt_row + NN;                        // NN
    int*                rowstart = cnt_col + NN;                        // NN+1
    int*                cursor   = rowstart + NN + 1;                   // NN
    float*              dinv     = (float*)(cursor + NN);               // NN
    int*                bsum     = (int*)(dinv + NN);                   // 64
    int*                boffset  = bsum + 64;                           // 64

    hipMemsetAsync(cnt_row, 0, 2 * NN * sizeof(int), stream);

    pack_kernel<<<NN / 4, 256, 0, stream>>>(x, mask, mx, bits);
    hist_kernel<<<(NE + 255) / 256, 256, 0, stream>>>(row, col, cnt_row, cnt_col);
    dinv_kernel<<<(NN + 255) / 256, 256, 0, stream>>>(cnt_col, dinv);
    scan_a<<<SNB, 256, 0, stream>>>(cnt_row, bsum);
    scan_b<<<1, 64, 0, stream>>>(bsum, boffset, rowstart);
    scan_c<<<SNB, 256, 0, stream>>>(cnt_row, boffset, rowstart, cursor);
    sort_kernel<<<(NE + 255) / 256, 256, 0, stream>>>(row, col, cursor, srcs);
    gather_kernel<<<NN / 4, 256, 0, stream>>>(rowstart, srcs, dinv, mx, bits, out);
    gemm_kernel<<<(NN + 31) / 32, 256, 0, stream>>>(out, W, b, out);
}

// Round 4
// 266.577 us; speedup vs baseline: 8.2011x; 1.2192x over previous
//
#include <hip/hip_runtime.h>
#include <math.h>

#define NN 50000
#define NE 640000
#define F  128
#define SCHUNK 1024
#define SNB 49   // ceil(NN/SCHUNK)
#define WPAD 136 // 128 + 8 ushort pad: row stride 272 B -> only 2-way bank aliasing (free)

typedef __attribute__((ext_vector_type(8))) short short8;
typedef __attribute__((ext_vector_type(4))) float floatx4;

__device__ inline unsigned f2bf_pk(float f0, float f1) {
    unsigned u0 = __float_as_uint(f0), u1 = __float_as_uint(f1);
    u0 = (u0 + 0x7fffu + ((u0 >> 16) & 1u)) >> 16;   // RNE
    u1 = (u1 + 0x7fffu + ((u1 >> 16) & 1u)) >> 16;
    return (u1 << 16) | u0;
}

// ---- pack: mx[n][f] = bf16(mask*nan_to_num(x)), bits[n] = 128-bit mask ----
__global__ __launch_bounds__(256) void pack_kernel(const float* __restrict__ x,
                                                   const float* __restrict__ mask,
                                                   unsigned* __restrict__ mx,
                                                   unsigned long long* __restrict__ bits) {
    int lane = threadIdx.x & 63;
    int n = blockIdx.x * 4 + (threadIdx.x >> 6);   // NN = 12500*4
    float2 xv = ((const float2*)x)[(size_t)n * 64 + lane];
    float2 mv = ((const float2*)mask)[(size_t)n * 64 + lane];
    float x0 = (xv.x != xv.x) ? 0.f : xv.x;
    float x1 = (xv.y != xv.y) ? 0.f : xv.y;
    float p0 = (mv.x != 0.f) ? x0 : 0.f;
    float p1 = (mv.y != 0.f) ? x1 : 0.f;
    mx[(size_t)n * 64 + lane] = f2bf_pk(p0, p1);
    unsigned long long b0 = __ballot(mv.x != 0.f);
    unsigned long long b1 = __ballot(mv.y != 0.f);
    if (lane == 0) {
        bits[2 * (size_t)n]     = b0;
        bits[2 * (size_t)n + 1] = b1;
    }
}

// ---- histogram ----
__global__ __launch_bounds__(256) void hist_kernel(const int* __restrict__ row,
                                                   const int* __restrict__ col,
                                                   int* __restrict__ cnt_row,
                                                   int* __restrict__ cnt_col) {
    int e = blockIdx.x * 256 + threadIdx.x;
    if (e < NE) {
        atomicAdd(&cnt_row[row[e]], 1);
        atomicAdd(&cnt_col[col[e]], 1);
    }
}

__global__ __launch_bounds__(256) void dinv_kernel(const int* __restrict__ cnt_col,
                                                   float* __restrict__ dinv) {
    int i = blockIdx.x * 256 + threadIdx.x;
    if (i < NN) {
        int d = cnt_col[i];
        dinv[i] = (d > 0) ? rsqrtf((float)d) : 0.0f;
    }
}

// ---- 3-phase parallel exclusive scan of cnt_row ----
__global__ __launch_bounds__(256) void scan_a(const int* __restrict__ cnt,
                                              int* __restrict__ bsum) {
    int base = blockIdx.x * SCHUNK + threadIdx.x * 4;
    int s = 0;
    #pragma unroll
    for (int k = 0; k < 4; k++) { int i = base + k; if (i < NN) s += cnt[i]; }
    #pragma unroll
    for (int off = 32; off; off >>= 1) s += __shfl_down(s, off);
    __shared__ int ws[4];
    int lane = threadIdx.x & 63, wid = threadIdx.x >> 6;
    if (lane == 0) ws[wid] = s;
    __syncthreads();
    if (threadIdx.x == 0) bsum[blockIdx.x] = ws[0] + ws[1] + ws[2] + ws[3];
}

__global__ void scan_b(const int* __restrict__ bsum, int* __restrict__ boffset,
                       int* __restrict__ rowstart) {
    int l = threadIdx.x;
    int v = (l < SNB) ? bsum[l] : 0;
    int incl = v;
    #pragma unroll
    for (int off = 1; off < 64; off <<= 1) {
        int t = __shfl_up(incl, off);
        if (l >= off) incl += t;
    }
    if (l < SNB) boffset[l] = incl - v;
    if (l == 63) rowstart[NN] = incl;
}

__global__ __launch_bounds__(256) void scan_c(const int* __restrict__ cnt,
                                              const int* __restrict__ boffset,
                                              int* __restrict__ rowstart,
                                              int* __restrict__ cursor) {
    int base = blockIdx.x * SCHUNK + threadIdx.x * 4;
    int v[4]; int ts = 0;
    #pragma unroll
    for (int k = 0; k < 4; k++) { int i = base + k; v[k] = (i < NN) ? cnt[i] : 0; ts += v[k]; }
    int lane = threadIdx.x & 63, wid = threadIdx.x >> 6;
    int incl = ts;
    #pragma unroll
    for (int off = 1; off < 64; off <<= 1) {
        int t = __shfl_up(incl, off);
        if (lane >= off) incl += t;
    }
    __shared__ int ws[4];
    if (lane == 63) ws[wid] = incl;
    __syncthreads();
    int wbase = 0;
    for (int k = 0; k < wid; k++) wbase += ws[k];
    int run = boffset[blockIdx.x] + wbase + incl - ts;
    #pragma unroll
    for (int k = 0; k < 4; k++) {
        int i = base + k;
        if (i < NN) { rowstart[i] = run; cursor[i] = run; }
        run += v[k];
    }
}

// ---- counting-sort scatter ----
__global__ __launch_bounds__(256) void sort_kernel(const int* __restrict__ row,
                                                   const int* __restrict__ col,
                                                   int* __restrict__ cursor,
                                                   int* __restrict__ srcs) {
    int e = blockIdx.x * 256 + threadIdx.x;
    if (e < NE) {
        int p = atomicAdd(&cursor[row[e]], 1);
        srcs[p] = col[e];
    }
}

// ---- gather + fused ratio: one wave per dst node, bf16 mx + bitmask den ----
__global__ __launch_bounds__(256) void gather_kernel(
        const int* __restrict__ rowstart, const int* __restrict__ srcs,
        const float* __restrict__ dinv,
        const unsigned* __restrict__ mx, const unsigned long long* __restrict__ bits,
        float* __restrict__ ratio) {
    int lane = threadIdx.x & 63;
    int r = blockIdx.x * 4 + (threadIdx.x >> 6);
    int s0 = rowstart[r], s1 = rowstart[r + 1];
    float dr = dinv[r];
    float n0 = 0.f, n1 = 0.f, d0 = 0.f, d1 = 0.f, S = 0.f;

    int j = s0;
    for (; j + 1 < s1; j += 2) {
        int ca = srcs[j], cb = srcs[j + 1];
        float wa = dinv[ca], wb = dinv[cb];
        unsigned ua = mx[(size_t)ca * 64 + lane];
        unsigned ub = mx[(size_t)cb * 64 + lane];
        ulonglong2 ba = ((const ulonglong2*)bits)[ca];
        ulonglong2 bb = ((const ulonglong2*)bits)[cb];
        float fa0 = __uint_as_float(ua << 16);
        float fa1 = __uint_as_float(ua & 0xffff0000u);
        float fb0 = __uint_as_float(ub << 16);
        float fb1 = __uint_as_float(ub & 0xffff0000u);
        S += wa + wb;
        n0 += wa * fa0 + wb * fb0;
        n1 += wa * fa1 + wb * fb1;
        d0 += (((ba.x >> lane) & 1ull) ? wa : 0.f) + (((bb.x >> lane) & 1ull) ? wb : 0.f);
        d1 += (((ba.y >> lane) & 1ull) ? wa : 0.f) + (((bb.y >> lane) & 1ull) ? wb : 0.f);
    }
    if (j < s1) {
        int ca = srcs[j];
        float wa = dinv[ca];
        unsigned ua = mx[(size_t)ca * 64 + lane];
        ulonglong2 ba = ((const ulonglong2*)bits)[ca];
        float fa0 = __uint_as_float(ua << 16);
        float fa1 = __uint_as_float(ua & 0xffff0000u);
        S += wa;
        n0 += wa * fa0;
        n1 += wa * fa1;
        d0 += ((ba.x >> lane) & 1ull) ? wa : 0.f;
        d1 += ((ba.y >> lane) & 1ull) ? wa : 0.f;
    }

    float k = dr * S;
    float2 o;
    o.x = (d0 != 0.f) ? k * n0 / d0 : 0.f;
    o.y = (d1 != 0.f) ? k * n1 / d1 : 0.f;
    ((float2*)ratio)[(size_t)r * 64 + lane] = o;
}

// ---- out = A @ W^T + b via MFMA bf16 (in-place safe: block reads only rows it writes) ----
// block = 4 waves, 64 rows; W staged to LDS as bf16 (padded rows); 32 mfma/wave
__global__ __launch_bounds__(256) void gemm_kernel(const float* __restrict__ A,
                                                   const float* __restrict__ W,
                                                   const float* __restrict__ bias,
                                                   float* __restrict__ out) {
    __shared__ unsigned short Wlds[F * WPAD];   // 34816 B
    int tid = threadIdx.x;

    // stage W (fp32 row-major [c][k]) -> bf16 LDS, same layout, padded stride
    for (int i = tid * 4; i < F * F; i += 256 * 4) {
        int c = i >> 7, k = i & 127;
        float4 v = *(const float4*)(W + i);
        unsigned lo = f2bf_pk(v.x, v.y);
        unsigned hi = f2bf_pk(v.z, v.w);
        *(uint2*)&Wlds[c * WPAD + k] = make_uint2(lo, hi);
    }
    __syncthreads();

    int lane = tid & 63, wid = tid >> 6;
    int m = lane & 15, quad = lane >> 4;   // A row = m, k-offset = quad*8
    int arow = blockIdx.x * 64 + wid * 16 + m;
    int lrow = (arow < NN) ? arow : (NN - 1);       // clamp loads in-bounds
    const float* Arow = A + (size_t)lrow * F + quad * 8;

    floatx4 acc[8];
    #pragma unroll
    for (int nt = 0; nt < 8; nt++) acc[nt] = (floatx4)(0.f);

    #pragma unroll
    for (int step = 0; step < 4; step++) {
        float4 a0 = *(const float4*)(Arow + step * 32);
        float4 a1 = *(const float4*)(Arow + step * 32 + 4);
        union { short8 s; unsigned u[4]; } af;
        af.u[0] = f2bf_pk(a0.x, a0.y);
        af.u[1] = f2bf_pk(a0.z, a0.w);
        af.u[2] = f2bf_pk(a1.x, a1.y);
        af.u[3] = f2bf_pk(a1.z, a1.w);
        #pragma unroll
        for (int nt = 0; nt < 8; nt++) {
            short8 bf = *(const short8*)&Wlds[(nt * 16 + m) * WPAD + step * 32 + quad * 8];
            acc[nt] = __builtin_amdgcn_mfma_f32_16x16x32_bf16(af.s, bf, acc[nt], 0, 0, 0);
        }
    }

    // epilogue: C layout col = lane&15, row = quad*4 + reg
    int orow0 = blockIdx.x * 64 + wid * 16 + quad * 4;
    #pragma unroll
    for (int nt = 0; nt < 8; nt++) {
        float bv = bias[nt * 16 + m];
        #pragma unroll
        for (int p = 0; p < 4; p++) {
            int gr = orow0 + p;
            if (gr < NN) out[(size_t)gr * F + nt * 16 + m] = acc[nt][p] + bv;
        }
    }
}

extern "C" void kernel_launch(void* const* d_in, const int* in_sizes, int n_in,
                              void* d_out, int out_size, void* d_ws, size_t ws_size,
                              hipStream_t stream) {
    const float* x    = (const float*)d_in[0];
    const float* mask = (const float*)d_in[1];
    const int*   ei   = (const int*)d_in[2];
    const float* W    = (const float*)d_in[3];
    const float* b    = (const float*)d_in[4];
    float* out = (float*)d_out;

    const int* row = ei;
    const int* col = ei + NE;

    // ws layout
    unsigned*           mx       = (unsigned*)d_ws;                     // NN*64 (12.8 MB)
    unsigned long long* bits     = (unsigned long long*)(mx + (size_t)NN * 64);
    int*                srcs     = (int*)(bits + (size_t)NN * 2);       // NE
    int*                cnt_row  = srcs + NE;                           // NN
    int*                cnt_col  = cnt_row + NN;                        // NN
    int*                rowstart = cnt_col + NN;                        // NN+1
    int*                cursor   = rowstart + NN + 1;                   // NN
    float*              dinv     = (float*)(cursor + NN);               // NN
    int*                bsum     = (int*)(dinv + NN);                   // 64
    int*                boffset  = bsum + 64;                           // 64

    hipMemsetAsync(cnt_row, 0, 2 * NN * sizeof(int), stream);

    pack_kernel<<<NN / 4, 256, 0, stream>>>(x, mask, mx, bits);
    hist_kernel<<<(NE + 255) / 256, 256, 0, stream>>>(row, col, cnt_row, cnt_col);
    dinv_kernel<<<(NN + 255) / 256, 256, 0, stream>>>(cnt_col, dinv);
    scan_a<<<SNB, 256, 0, stream>>>(cnt_row, bsum);
    scan_b<<<1, 64, 0, stream>>>(bsum, boffset, rowstart);
    scan_c<<<SNB, 256, 0, stream>>>(cnt_row, boffset, rowstart, cursor);
    sort_kernel<<<(NE + 255) / 256, 256, 0, stream>>>(row, col, cursor, srcs);
    gather_kernel<<<NN / 4, 256, 0, stream>>>(rowstart, srcs, dinv, mx, bits, out);
    gemm_kernel<<<(NN + 63) / 64, 256, 0, stream>>>(out, W, b, out);
}

// Round 5
// 253.687 us; speedup vs baseline: 8.6178x; 1.0508x over previous
//
#include <hip/hip_runtime.h>
#include <math.h>

#define NN 50000
#define NE 640000
#define F  128
#define SCHUNK 1024
#define SNB 49   // ceil(NN/SCHUNK)
#define WPAD 136 // 128 + 8 ushort pad

typedef __attribute__((ext_vector_type(8))) short short8;
typedef __attribute__((ext_vector_type(4))) float floatx4;

__device__ inline unsigned f2bf_pk(float f0, float f1) {
    unsigned u0 = __float_as_uint(f0), u1 = __float_as_uint(f1);
    u0 = (u0 + 0x7fffu + ((u0 >> 16) & 1u)) >> 16;   // RNE
    u1 = (u1 + 0x7fffu + ((u1 >> 16) & 1u)) >> 16;
    return (u1 << 16) | u0;
}

// interleave two 4-bit nibbles: bit 2j = a_j, bit 2j+1 = b_j
__device__ inline unsigned ilv4(unsigned a, unsigned b) {
    a = (a | (a << 2)) & 0x33u; a = (a | (a << 1)) & 0x55u;
    b = (b | (b << 2)) & 0x33u; b = (b | (b << 1)) & 0x55u;
    return a | (b << 1);
}

// ---- pack: mx[n] = 128 bf16 of mask*nan_to_num(x); bits8[n][l16] = 8 mask bits ----
__global__ __launch_bounds__(256) void pack_kernel(const float* __restrict__ x,
                                                   const float* __restrict__ mask,
                                                   unsigned* __restrict__ mx,
                                                   unsigned char* __restrict__ bits8) {
    int lane = threadIdx.x & 63;
    int n = blockIdx.x * 4 + (threadIdx.x >> 6);   // NN = 12500*4
    float2 xv = ((const float2*)x)[(size_t)n * 64 + lane];
    float2 mv = ((const float2*)mask)[(size_t)n * 64 + lane];
    float x0 = (xv.x != xv.x) ? 0.f : xv.x;
    float x1 = (xv.y != xv.y) ? 0.f : xv.y;
    float p0 = (mv.x != 0.f) ? x0 : 0.f;
    float p1 = (mv.y != 0.f) ? x1 : 0.f;
    mx[(size_t)n * 64 + lane] = f2bf_pk(p0, p1);
    unsigned long long b0 = __ballot(mv.x != 0.f);   // bit p = mask[2p]
    unsigned long long b1 = __ballot(mv.y != 0.f);   // bit p = mask[2p+1]
    if (lane < 16) {
        unsigned nib0 = (unsigned)(b0 >> (4 * lane)) & 0xFu;
        unsigned nib1 = (unsigned)(b1 >> (4 * lane)) & 0xFu;
        bits8[(size_t)n * 16 + lane] = (unsigned char)ilv4(nib0, nib1);
    }
}

// ---- histogram, 8 XCD-privatized copies ----
__global__ __launch_bounds__(256) void hist_kernel(const int* __restrict__ row,
                                                   const int* __restrict__ col,
                                                   int* __restrict__ cnt_row8,
                                                   int* __restrict__ cnt_col8) {
    int e = blockIdx.x * 256 + threadIdx.x;
    int k = blockIdx.x & 7;
    if (e < NE) {
        atomicAdd(&cnt_row8[k * NN + row[e]], 1);
        atomicAdd(&cnt_col8[k * NN + col[e]], 1);
    }
}

// ---- reduce copies: dinv from col counts, total row counts for scan ----
__global__ __launch_bounds__(256) void dinv_kernel(const int* __restrict__ cnt_col8,
                                                   const int* __restrict__ cnt_row8,
                                                   float* __restrict__ dinv,
                                                   int* __restrict__ cnt_row) {
    int i = blockIdx.x * 256 + threadIdx.x;
    if (i < NN) {
        int sc = 0, sr = 0;
        #pragma unroll
        for (int k = 0; k < 8; k++) {
            sc += cnt_col8[k * NN + i];
            sr += cnt_row8[k * NN + i];
        }
        dinv[i] = (sc > 0) ? rsqrtf((float)sc) : 0.0f;
        cnt_row[i] = sr;
    }
}

// ---- 3-phase parallel exclusive scan of cnt_row ----
__global__ __launch_bounds__(256) void scan_a(const int* __restrict__ cnt,
                                              int* __restrict__ bsum) {
    int base = blockIdx.x * SCHUNK + threadIdx.x * 4;
    int s = 0;
    #pragma unroll
    for (int k = 0; k < 4; k++) { int i = base + k; if (i < NN) s += cnt[i]; }
    #pragma unroll
    for (int off = 32; off; off >>= 1) s += __shfl_down(s, off);
    __shared__ int ws[4];
    int lane = threadIdx.x & 63, wid = threadIdx.x >> 6;
    if (lane == 0) ws[wid] = s;
    __syncthreads();
    if (threadIdx.x == 0) bsum[blockIdx.x] = ws[0] + ws[1] + ws[2] + ws[3];
}

__global__ void scan_b(const int* __restrict__ bsum, int* __restrict__ boffset,
                       int* __restrict__ rowstart) {
    int l = threadIdx.x;
    int v = (l < SNB) ? bsum[l] : 0;
    int incl = v;
    #pragma unroll
    for (int off = 1; off < 64; off <<= 1) {
        int t = __shfl_up(incl, off);
        if (l >= off) incl += t;
    }
    if (l < SNB) boffset[l] = incl - v;
    if (l == 63) rowstart[NN] = incl;
}

__global__ __launch_bounds__(256) void scan_c(const int* __restrict__ cnt,
                                              const int* __restrict__ boffset,
                                              int* __restrict__ rowstart) {
    int base = blockIdx.x * SCHUNK + threadIdx.x * 4;
    int v[4]; int ts = 0;
    #pragma unroll
    for (int k = 0; k < 4; k++) { int i = base + k; v[k] = (i < NN) ? cnt[i] : 0; ts += v[k]; }
    int lane = threadIdx.x & 63, wid = threadIdx.x >> 6;
    int incl = ts;
    #pragma unroll
    for (int off = 1; off < 64; off <<= 1) {
        int t = __shfl_up(incl, off);
        if (lane >= off) incl += t;
    }
    __shared__ int ws[4];
    if (lane == 63) ws[wid] = incl;
    __syncthreads();
    int wbase = 0;
    for (int k = 0; k < wid; k++) wbase += ws[k];
    int run = boffset[blockIdx.x] + wbase + incl - ts;
    #pragma unroll
    for (int k = 0; k < 4; k++) {
        int i = base + k;
        if (i < NN) rowstart[i] = run;
        run += v[k];
    }
}

// ---- per-copy cursor bases: cursor8[k][r] = rowstart[r] + sum_{j<k} cnt_row8[j][r] ----
__global__ __launch_bounds__(256) void cursors_kernel(const int* __restrict__ rowstart,
                                                      const int* __restrict__ cnt_row8,
                                                      int* __restrict__ cursor8) {
    int i = blockIdx.x * 256 + threadIdx.x;
    if (i < NN) {
        int base = rowstart[i];
        #pragma unroll
        for (int k = 0; k < 8; k++) {
            cursor8[k * NN + i] = base;
            base += cnt_row8[k * NN + i];
        }
    }
}

// ---- counting-sort scatter with XCD-privatized cursors ----
__global__ __launch_bounds__(256) void sort_kernel(const int* __restrict__ row,
                                                   const int* __restrict__ col,
                                                   int* __restrict__ cursor8,
                                                   int* __restrict__ srcs) {
    int e = blockIdx.x * 256 + threadIdx.x;
    int k = blockIdx.x & 7;
    if (e < NE) {
        int p = atomicAdd(&cursor8[k * NN + row[e]], 1);
        srcs[p] = col[e];
    }
}

// ---- gather + fused ratio: one wave per dst node, 4 edges in flight ----
// lane = (sub, l16): sub = edge slot, l16 = 8-feature slice (uint4 of mx)
__global__ __launch_bounds__(256) void gather_kernel(
        const int* __restrict__ rowstart, const int* __restrict__ srcs,
        const float* __restrict__ dinv,
        const uint4* __restrict__ mxv, const unsigned char* __restrict__ bits8,
        float* __restrict__ ratio) {
    int lane = threadIdx.x & 63;
    int r = blockIdx.x * 4 + (threadIdx.x >> 6);
    int l16 = lane & 15, sub = lane >> 4;
    int s0 = rowstart[r], s1 = rowstart[r + 1];
    float dr = dinv[r];
    float num[8] = {0.f,0.f,0.f,0.f,0.f,0.f,0.f,0.f};
    float den[8] = {0.f,0.f,0.f,0.f,0.f,0.f,0.f,0.f};
    float S = 0.f;

    for (int j = s0; j < s1; j += 4) {
        int jj = j + sub;
        int cl = (jj < s1) ? jj : (s1 - 1);
        int c = srcs[cl];
        float w = (jj < s1) ? dinv[c] : 0.f;
        uint4 u = mxv[(size_t)c * 16 + l16];
        unsigned mb = bits8[(size_t)c * 16 + l16];
        float f[8];
        f[0] = __uint_as_float(u.x << 16); f[1] = __uint_as_float(u.x & 0xffff0000u);
        f[2] = __uint_as_float(u.y << 16); f[3] = __uint_as_float(u.y & 0xffff0000u);
        f[4] = __uint_as_float(u.z << 16); f[5] = __uint_as_float(u.z & 0xffff0000u);
        f[6] = __uint_as_float(u.w << 16); f[7] = __uint_as_float(u.w & 0xffff0000u);
        S += w;
        #pragma unroll
        for (int q = 0; q < 8; q++) {
            num[q] += w * f[q];
            den[q] += ((mb >> q) & 1u) ? w : 0.f;
        }
    }

    // reduce across sub (lane bits 4,5)
    #pragma unroll
    for (int q = 0; q < 8; q++) {
        num[q] += __shfl_xor(num[q], 16); num[q] += __shfl_xor(num[q], 32);
        den[q] += __shfl_xor(den[q], 16); den[q] += __shfl_xor(den[q], 32);
    }
    S += __shfl_xor(S, 16); S += __shfl_xor(S, 32);

    if (sub == 0) {
        float kf = dr * S;
        float o[8];
        #pragma unroll
        for (int q = 0; q < 8; q++)
            o[q] = (den[q] != 0.f) ? kf * num[q] / den[q] : 0.f;
        float4* outp = (float4*)(ratio + (size_t)r * F + l16 * 8);
        outp[0] = make_float4(o[0], o[1], o[2], o[3]);
        outp[1] = make_float4(o[4], o[5], o[6], o[7]);
    }
}

// ---- out = A @ W^T + b via MFMA bf16 (in-place safe per 64-row block) ----
__global__ __launch_bounds__(256) void gemm_kernel(const float* __restrict__ A,
                                                   const float* __restrict__ W,
                                                   const float* __restrict__ bias,
                                                   float* __restrict__ out) {
    __shared__ unsigned short Wlds[F * WPAD];
    int tid = threadIdx.x;

    for (int i = tid * 4; i < F * F; i += 256 * 4) {
        int c = i >> 7, k = i & 127;
        float4 v = *(const float4*)(W + i);
        unsigned lo = f2bf_pk(v.x, v.y);
        unsigned hi = f2bf_pk(v.z, v.w);
        *(uint2*)&Wlds[c * WPAD + k] = make_uint2(lo, hi);
    }
    __syncthreads();

    int lane = tid & 63, wid = tid >> 6;
    int m = lane & 15, quad = lane >> 4;
    int arow = blockIdx.x * 64 + wid * 16 + m;
    int lrow = (arow < NN) ? arow : (NN - 1);
    const float* Arow = A + (size_t)lrow * F + quad * 8;

    floatx4 acc[8];
    #pragma unroll
    for (int nt = 0; nt < 8; nt++) acc[nt] = (floatx4)(0.f);

    #pragma unroll
    for (int step = 0; step < 4; step++) {
        float4 a0 = *(const float4*)(Arow + step * 32);
        float4 a1 = *(const float4*)(Arow + step * 32 + 4);
        union { short8 s; unsigned u[4]; } af;
        af.u[0] = f2bf_pk(a0.x, a0.y);
        af.u[1] = f2bf_pk(a0.z, a0.w);
        af.u[2] = f2bf_pk(a1.x, a1.y);
        af.u[3] = f2bf_pk(a1.z, a1.w);
        #pragma unroll
        for (int nt = 0; nt < 8; nt++) {
            short8 bf = *(const short8*)&Wlds[(nt * 16 + m) * WPAD + step * 32 + quad * 8];
            acc[nt] = __builtin_amdgcn_mfma_f32_16x16x32_bf16(af.s, bf, acc[nt], 0, 0, 0);
        }
    }

    int orow0 = blockIdx.x * 64 + wid * 16 + quad * 4;
    #pragma unroll
    for (int nt = 0; nt < 8; nt++) {
        float bv = bias[nt * 16 + m];
        #pragma unroll
        for (int p = 0; p < 4; p++) {
            int gr = orow0 + p;
            if (gr < NN) out[(size_t)gr * F + nt * 16 + m] = acc[nt][p] + bv;
        }
    }
}

extern "C" void kernel_launch(void* const* d_in, const int* in_sizes, int n_in,
                              void* d_out, int out_size, void* d_ws, size_t ws_size,
                              hipStream_t stream) {
    const float* x    = (const float*)d_in[0];
    const float* mask = (const float*)d_in[1];
    const int*   ei   = (const int*)d_in[2];
    const float* W    = (const float*)d_in[3];
    const float* b    = (const float*)d_in[4];
    float* out = (float*)d_out;

    const int* row = ei;
    const int* col = ei + NE;

    // ws layout
    unsigned*      mx       = (unsigned*)d_ws;                       // NN*64 u32 (12.8 MB)
    unsigned char* bits8    = (unsigned char*)(mx + (size_t)NN * 64); // NN*16 B (800 KB)
    int*           srcs     = (int*)(bits8 + (size_t)NN * 16);        // NE
    int*           cnt_row8 = srcs + NE;                              // 8*NN
    int*           cnt_col8 = cnt_row8 + 8 * NN;                      // 8*NN
    int*           cursor8  = cnt_col8 + 8 * NN;                      // 8*NN
    int*           cnt_row  = cursor8 + 8 * NN;                       // NN
    int*           rowstart = cnt_row + NN;                           // NN+1
    float*         dinv     = (float*)(rowstart + NN + 1);            // NN
    int*           bsum     = (int*)(dinv + NN);                      // 64
    int*           boffset  = bsum + 64;                              // 64

    hipMemsetAsync(cnt_row8, 0, 16 * NN * sizeof(int), stream);

    pack_kernel<<<NN / 4, 256, 0, stream>>>(x, mask, mx, bits8);
    hist_kernel<<<(NE + 255) / 256, 256, 0, stream>>>(row, col, cnt_row8, cnt_col8);
    dinv_kernel<<<(NN + 255) / 256, 256, 0, stream>>>(cnt_col8, cnt_row8, dinv, cnt_row);
    scan_a<<<SNB, 256, 0, stream>>>(cnt_row, bsum);
    scan_b<<<1, 64, 0, stream>>>(bsum, boffset, rowstart);
    scan_c<<<SNB, 256, 0, stream>>>(cnt_row, boffset, rowstart);
    cursors_kernel<<<(NN + 255) / 256, 256, 0, stream>>>(rowstart, cnt_row8, cursor8);
    sort_kernel<<<(NE + 255) / 256, 256, 0, stream>>>(row, col, cursor8, srcs);
    gather_kernel<<<NN / 4, 256, 0, stream>>>(rowstart, srcs, dinv,
                                              (const uint4*)mx, bits8, out);
    gemm_kernel<<<(NN + 63) / 64, 256, 0, stream>>>(out, W, b, out);
}

// Round 6
// 212.079 us; speedup vs baseline: 10.3086x; 1.1962x over previous
//
#include <hip/hip_runtime.h>
#include <math.h>

#define NN 50000
#define NE 640000
#define F  128
#define NB 196        // coarse buckets of 256 nodes: (NN+255)>>8
#define ECHUNK 2500   // NE / 256 blocks
#define WPAD 136      // 128 + 8 ushort pad

typedef __attribute__((ext_vector_type(8))) short short8;
typedef __attribute__((ext_vector_type(4))) float floatx4;

__device__ inline unsigned f2bf_pk(float f0, float f1) {
    unsigned u0 = __float_as_uint(f0), u1 = __float_as_uint(f1);
    u0 = (u0 + 0x7fffu + ((u0 >> 16) & 1u)) >> 16;   // RNE
    u1 = (u1 + 0x7fffu + ((u1 >> 16) & 1u)) >> 16;
    return (u1 << 16) | u0;
}

__device__ inline unsigned ilv4(unsigned a, unsigned b) {
    a = (a | (a << 2)) & 0x33u; a = (a | (a << 1)) & 0x55u;
    b = (b | (b << 2)) & 0x33u; b = (b | (b << 1)) & 0x55u;
    return a | (b << 1);
}

// ---- pack: mx[n] = 128 bf16 of mask*nan_to_num(x); bits8[n][l16] = 8 mask bits ----
__global__ __launch_bounds__(256) void pack_kernel(const float* __restrict__ x,
                                                   const float* __restrict__ mask,
                                                   unsigned* __restrict__ mx,
                                                   unsigned char* __restrict__ bits8) {
    int lane = threadIdx.x & 63;
    int n = blockIdx.x * 4 + (threadIdx.x >> 6);   // NN = 12500*4
    float2 xv = ((const float2*)x)[(size_t)n * 64 + lane];
    float2 mv = ((const float2*)mask)[(size_t)n * 64 + lane];
    float x0 = (xv.x != xv.x) ? 0.f : xv.x;
    float x1 = (xv.y != xv.y) ? 0.f : xv.y;
    float p0 = (mv.x != 0.f) ? x0 : 0.f;
    float p1 = (mv.y != 0.f) ? x1 : 0.f;
    mx[(size_t)n * 64 + lane] = f2bf_pk(p0, p1);
    unsigned long long b0 = __ballot(mv.x != 0.f);
    unsigned long long b1 = __ballot(mv.y != 0.f);
    if (lane < 16) {
        unsigned nib0 = (unsigned)(b0 >> (4 * lane)) & 0xFu;
        unsigned nib1 = (unsigned)(b1 >> (4 * lane)) & 0xFu;
        bits8[(size_t)n * 16 + lane] = (unsigned char)ilv4(nib0, nib1);
    }
}

// ---- K1: coarse histograms (196 bins) via LDS, merged with counted atomics ----
__global__ __launch_bounds__(256) void chist_kernel(const int* __restrict__ row,
                                                    const int* __restrict__ col,
                                                    int* __restrict__ crow,
                                                    int* __restrict__ ccol) {
    __shared__ int hr[NB], hc[NB];
    for (int i = threadIdx.x; i < NB; i += 256) { hr[i] = 0; hc[i] = 0; }
    __syncthreads();
    int e0 = blockIdx.x * ECHUNK, e1 = e0 + ECHUNK;
    for (int e = e0 + threadIdx.x; e < e1; e += 256) {
        atomicAdd(&hr[row[e] >> 8], 1);
        atomicAdd(&hc[col[e] >> 8], 1);
    }
    __syncthreads();
    for (int i = threadIdx.x; i < NB; i += 256) {
        atomicAdd(&crow[i], hr[i]);
        atomicAdd(&ccol[i], hc[i]);
    }
}

// ---- K2: scan both coarse hists -> bases + cursors; rowstart[NN] = NE ----
__global__ __launch_bounds__(256) void cscan_kernel(const int* __restrict__ crow,
                                                    const int* __restrict__ ccol,
                                                    int* __restrict__ crow_base,
                                                    int* __restrict__ ccol_base,
                                                    int* __restrict__ crow_cur,
                                                    int* __restrict__ ccol_cur,
                                                    int* __restrict__ rowstart) {
    __shared__ int ws[4];
    int t = threadIdx.x, lane = t & 63, wid = t >> 6;
    {
        int v = (t < NB) ? crow[t] : 0;
        int incl = v;
        #pragma unroll
        for (int off = 1; off < 64; off <<= 1) { int s = __shfl_up(incl, off); if (lane >= off) incl += s; }
        if (lane == 63) ws[wid] = incl;
        __syncthreads();
        int wbase = 0;
        for (int k = 0; k < wid; k++) wbase += ws[k];
        int ex = wbase + incl - v;
        if (t < NB) { crow_base[t] = ex; crow_cur[t] = ex; }
        if (t == 0) { crow_base[NB] = NE; rowstart[NN] = NE; }
        __syncthreads();
    }
    {
        int v = (t < NB) ? ccol[t] : 0;
        int incl = v;
        #pragma unroll
        for (int off = 1; off < 64; off <<= 1) { int s = __shfl_up(incl, off); if (lane >= off) incl += s; }
        if (lane == 63) ws[wid] = incl;
        __syncthreads();
        int wbase = 0;
        for (int k = 0; k < wid; k++) wbase += ws[k];
        int ex = wbase + incl - v;
        if (t < NB) { ccol_base[t] = ex; ccol_cur[t] = ex; }
        if (t == 0) ccol_base[NB] = NE;
    }
}

// ---- K3: bucket scatter. rrec = (row&255)<<16 | col keyed by row>>8; crec = col&255 keyed by col>>8 ----
__global__ __launch_bounds__(256) void scatter_kernel(const int* __restrict__ row,
                                                      const int* __restrict__ col,
                                                      int* __restrict__ crow_cur,
                                                      int* __restrict__ ccol_cur,
                                                      unsigned* __restrict__ rrec,
                                                      unsigned char* __restrict__ crec) {
    __shared__ int cntR[NB], cntC[NB], curR[NB], curC[NB];
    for (int i = threadIdx.x; i < NB; i += 256) { cntR[i] = 0; cntC[i] = 0; }
    __syncthreads();
    int e0 = blockIdx.x * ECHUNK, e1 = e0 + ECHUNK;
    for (int e = e0 + threadIdx.x; e < e1; e += 256) {
        atomicAdd(&cntR[row[e] >> 8], 1);
        atomicAdd(&cntC[col[e] >> 8], 1);
    }
    __syncthreads();
    for (int i = threadIdx.x; i < NB; i += 256) {
        curR[i] = atomicAdd(&crow_cur[i], cntR[i]);
        curC[i] = atomicAdd(&ccol_cur[i], cntC[i]);
    }
    __syncthreads();
    for (int e = e0 + threadIdx.x; e < e1; e += 256) {
        int r = row[e], c = col[e];
        int pr = atomicAdd(&curR[r >> 8], 1);
        rrec[pr] = ((unsigned)(r & 255) << 16) | (unsigned)c;
        int pc = atomicAdd(&curC[c >> 8], 1);
        crec[pc] = (unsigned char)(c & 255);
    }
}

// ---- K4: fine sort within row-bucket: writes rowstart + srcs (ushort cols) ----
__global__ __launch_bounds__(256) void finerow_kernel(const unsigned* __restrict__ rrec,
                                                      const int* __restrict__ crow_base,
                                                      int* __restrict__ rowstart,
                                                      unsigned short* __restrict__ srcs) {
    __shared__ int hist[256];
    __shared__ int ws[4];
    int b = blockIdx.x;
    int s0 = crow_base[b], s1 = crow_base[b + 1];
    int t = threadIdx.x, lane = t & 63, wid = t >> 6;
    hist[t] = 0;
    __syncthreads();
    for (int j = s0 + t; j < s1; j += 256)
        atomicAdd(&hist[(rrec[j] >> 16) & 255], 1);
    __syncthreads();
    int v = hist[t];
    int incl = v;
    #pragma unroll
    for (int off = 1; off < 64; off <<= 1) { int s = __shfl_up(incl, off); if (lane >= off) incl += s; }
    if (lane == 63) ws[wid] = incl;
    __syncthreads();
    int wbase = 0;
    for (int k = 0; k < wid; k++) wbase += ws[k];
    int ex = wbase + incl - v;
    int node = b * 256 + t;
    if (node < NN) rowstart[node] = s0 + ex;
    hist[t] = ex;          // reuse as in-bucket cursor
    __syncthreads();
    for (int j = s0 + t; j < s1; j += 256) {
        unsigned rec = rrec[j];
        int pos = atomicAdd(&hist[(rec >> 16) & 255], 1);
        srcs[s0 + pos] = (unsigned short)(rec & 0xFFFFu);
    }
}

// ---- K5: fine hist within col-bucket -> dinv directly ----
__global__ __launch_bounds__(256) void finecol_kernel(const unsigned char* __restrict__ crec,
                                                      const int* __restrict__ ccol_base,
                                                      float* __restrict__ dinv) {
    __shared__ int hist[256];
    int b = blockIdx.x;
    int s0 = ccol_base[b], s1 = ccol_base[b + 1];
    int t = threadIdx.x;
    hist[t] = 0;
    __syncthreads();
    for (int j = s0 + t; j < s1; j += 256)
        atomicAdd(&hist[crec[j]], 1);
    __syncthreads();
    int node = b * 256 + t;
    if (node < NN) {
        int d = hist[t];
        dinv[node] = (d > 0) ? rsqrtf((float)d) : 0.0f;
    }
}

// ---- gather + fused ratio: one wave per dst node, 4 edges in flight ----
__global__ __launch_bounds__(256) void gather_kernel(
        const int* __restrict__ rowstart, const unsigned short* __restrict__ srcs,
        const float* __restrict__ dinv,
        const uint4* __restrict__ mxv, const unsigned char* __restrict__ bits8,
        float* __restrict__ ratio) {
    int lane = threadIdx.x & 63;
    int r = blockIdx.x * 4 + (threadIdx.x >> 6);
    int l16 = lane & 15, sub = lane >> 4;
    int s0 = rowstart[r], s1 = rowstart[r + 1];
    float dr = dinv[r];
    float num[8] = {0.f,0.f,0.f,0.f,0.f,0.f,0.f,0.f};
    float den[8] = {0.f,0.f,0.f,0.f,0.f,0.f,0.f,0.f};
    float S = 0.f;

    for (int j = s0; j < s1; j += 4) {
        int jj = j + sub;
        int cl = (jj < s1) ? jj : (s1 - 1);
        int c = srcs[cl];
        float w = (jj < s1) ? dinv[c] : 0.f;
        uint4 u = mxv[(size_t)c * 16 + l16];
        unsigned mb = bits8[(size_t)c * 16 + l16];
        float f[8];
        f[0] = __uint_as_float(u.x << 16); f[1] = __uint_as_float(u.x & 0xffff0000u);
        f[2] = __uint_as_float(u.y << 16); f[3] = __uint_as_float(u.y & 0xffff0000u);
        f[4] = __uint_as_float(u.z << 16); f[5] = __uint_as_float(u.z & 0xffff0000u);
        f[6] = __uint_as_float(u.w << 16); f[7] = __uint_as_float(u.w & 0xffff0000u);
        S += w;
        #pragma unroll
        for (int q = 0; q < 8; q++) {
            num[q] += w * f[q];
            den[q] += ((mb >> q) & 1u) ? w : 0.f;
        }
    }

    #pragma unroll
    for (int q = 0; q < 8; q++) {
        num[q] += __shfl_xor(num[q], 16); num[q] += __shfl_xor(num[q], 32);
        den[q] += __shfl_xor(den[q], 16); den[q] += __shfl_xor(den[q], 32);
    }
    S += __shfl_xor(S, 16); S += __shfl_xor(S, 32);

    if (sub == 0) {
        float kf = dr * S;
        float o[8];
        #pragma unroll
        for (int q = 0; q < 8; q++)
            o[q] = (den[q] != 0.f) ? kf * num[q] / den[q] : 0.f;
        float4* outp = (float4*)(ratio + (size_t)r * F + l16 * 8);
        outp[0] = make_float4(o[0], o[1], o[2], o[3]);
        outp[1] = make_float4(o[4], o[5], o[6], o[7]);
    }
}

// ---- out = A @ W^T + b via MFMA bf16 (in-place safe: wave reads only its own rows) ----
__global__ __launch_bounds__(256) void gemm_kernel(const float* __restrict__ A,
                                                   const float* __restrict__ W,
                                                   const float* __restrict__ bias,
                                                   float* __restrict__ out) {
    __shared__ unsigned short Wlds[F * WPAD];
    int tid = threadIdx.x;

    for (int i = tid * 4; i < F * F; i += 256 * 4) {
        int c = i >> 7, k = i & 127;
        float4 v = *(const float4*)(W + i);
        unsigned lo = f2bf_pk(v.x, v.y);
        unsigned hi = f2bf_pk(v.z, v.w);
        *(uint2*)&Wlds[c * WPAD + k] = make_uint2(lo, hi);
    }
    __syncthreads();

    int lane = tid & 63, wid = tid >> 6;
    int m = lane & 15, quad = lane >> 4;
    int arow = blockIdx.x * 64 + wid * 16 + m;
    int lrow = (arow < NN) ? arow : (NN - 1);
    const float* Arow = A + (size_t)lrow * F + quad * 8;

    floatx4 acc[8];
    #pragma unroll
    for (int nt = 0; nt < 8; nt++) acc[nt] = (floatx4)(0.f);

    #pragma unroll
    for (int step = 0; step < 4; step++) {
        float4 a0 = *(const float4*)(Arow + step * 32);
        float4 a1 = *(const float4*)(Arow + step * 32 + 4);
        union { short8 s; unsigned u[4]; } af;
        af.u[0] = f2bf_pk(a0.x, a0.y);
        af.u[1] = f2bf_pk(a0.z, a0.w);
        af.u[2] = f2bf_pk(a1.x, a1.y);
        af.u[3] = f2bf_pk(a1.z, a1.w);
        #pragma unroll
        for (int nt = 0; nt < 8; nt++) {
            short8 bf = *(const short8*)&Wlds[(nt * 16 + m) * WPAD + step * 32 + quad * 8];
            acc[nt] = __builtin_amdgcn_mfma_f32_16x16x32_bf16(af.s, bf, acc[nt], 0, 0, 0);
        }
    }

    int orow0 = blockIdx.x * 64 + wid * 16 + quad * 4;
    #pragma unroll
    for (int nt = 0; nt < 8; nt++) {
        float bv = bias[nt * 16 + m];
        #pragma unroll
        for (int p = 0; p < 4; p++) {
            int gr = orow0 + p;
            if (gr < NN) out[(size_t)gr * F + nt * 16 + m] = acc[nt][p] + bv;
        }
    }
}

extern "C" void kernel_launch(void* const* d_in, const int* in_sizes, int n_in,
                              void* d_out, int out_size, void* d_ws, size_t ws_size,
                              hipStream_t stream) {
    const float* x    = (const float*)d_in[0];
    const float* mask = (const float*)d_in[1];
    const int*   ei   = (const int*)d_in[2];
    const float* W    = (const float*)d_in[3];
    const float* b    = (const float*)d_in[4];
    float* out = (float*)d_out;

    const int* row = ei;
    const int* col = ei + NE;

    // ws layout (all 4-byte aligned)
    unsigned*       mx        = (unsigned*)d_ws;                          // NN*64 u32 (12.8 MB)
    unsigned char*  bits8     = (unsigned char*)(mx + (size_t)NN * 64);   // NN*16 B
    unsigned short* srcs      = (unsigned short*)(bits8 + (size_t)NN * 16); // NE u16 (1.28 MB)
    unsigned*       rrec      = (unsigned*)(srcs + NE);                   // NE u32 (2.56 MB)
    unsigned char*  crec      = (unsigned char*)(rrec + NE);              // NE u8 (0.64 MB)
    int*            crow      = (int*)(crec + NE);                        // NB
    int*            ccol      = crow + NB;                                // NB
    int*            crow_base = ccol + NB;                                // NB+1
    int*            ccol_base = crow_base + NB + 1;                       // NB+1
    int*            crow_cur  = ccol_base + NB + 1;                       // NB
    int*            ccol_cur  = crow_cur + NB;                            // NB
    int*            rowstart  = ccol_cur + NB;                            // NN+1
    float*          dinv      = (float*)(rowstart + NN + 1);              // NN

    hipMemsetAsync(crow, 0, 2 * NB * sizeof(int), stream);

    pack_kernel<<<NN / 4, 256, 0, stream>>>(x, mask, mx, bits8);
    chist_kernel<<<256, 256, 0, stream>>>(row, col, crow, ccol);
    cscan_kernel<<<1, 256, 0, stream>>>(crow, ccol, crow_base, ccol_base,
                                        crow_cur, ccol_cur, rowstart);
    scatter_kernel<<<256, 256, 0, stream>>>(row, col, crow_cur, ccol_cur, rrec, crec);
    finerow_kernel<<<NB, 256, 0, stream>>>(rrec, crow_base, rowstart, srcs);
    finecol_kernel<<<NB, 256, 0, stream>>>(crec, ccol_base, dinv);
    gather_kernel<<<NN / 4, 256, 0, stream>>>(rowstart, srcs, dinv,
                                              (const uint4*)mx, bits8, out);
    gemm_kernel<<<(NN + 63) / 64, 256, 0, stream>>>(out, W, b, out);
}

// Round 7
// 197.051 us; speedup vs baseline: 11.0947x; 1.0763x over previous
//
#include <hip/hip_runtime.h>
#include <math.h>

#define NN 50000
#define NE 640000
#define F  128
#define NB 196        // coarse buckets of 256 nodes
#define PACKB 12500   // NN/4 pack blocks
#define CHB 256       // chist blocks
#define ECHUNK 2500   // NE / CHB
#define WPAD 136      // 128 + 8 ushort pad

typedef __attribute__((ext_vector_type(8))) short short8;
typedef __attribute__((ext_vector_type(4))) float floatx4;

__device__ inline unsigned f2bf_pk(float f0, float f1) {
    unsigned u0 = __float_as_uint(f0), u1 = __float_as_uint(f1);
    u0 = (u0 + 0x7fffu + ((u0 >> 16) & 1u)) >> 16;   // RNE
    u1 = (u1 + 0x7fffu + ((u1 >> 16) & 1u)) >> 16;
    return (u1 << 16) | u0;
}

__device__ inline unsigned ilv4(unsigned a, unsigned b) {
    a = (a | (a << 2)) & 0x33u; a = (a | (a << 1)) & 0x55u;
    b = (b | (b << 2)) & 0x33u; b = (b | (b << 1)) & 0x55u;
    return a | (b << 1);
}

// ---- fused: pack (blocks 0..PACKB) + coarse hist (blocks PACKB..PACKB+CHB) ----
// pack: mx[n] = 128 bf16 of mask*nan_to_num(x); rec[n][0..16) = mask bits
// chist: 196-bin LDS histograms of row>>8 / col>>8 merged via global atomics
__global__ __launch_bounds__(256) void pc_kernel(const float* __restrict__ x,
                                                 const float* __restrict__ mask,
                                                 const int* __restrict__ row,
                                                 const int* __restrict__ col,
                                                 unsigned* __restrict__ mx,
                                                 unsigned char* __restrict__ rec,
                                                 int* __restrict__ crow,
                                                 int* __restrict__ ccol) {
    if (blockIdx.x < PACKB) {
        int lane = threadIdx.x & 63;
        int n = blockIdx.x * 4 + (threadIdx.x >> 6);
        float2 xv = ((const float2*)x)[(size_t)n * 64 + lane];
        float2 mv = ((const float2*)mask)[(size_t)n * 64 + lane];
        float x0 = (xv.x != xv.x) ? 0.f : xv.x;
        float x1 = (xv.y != xv.y) ? 0.f : xv.y;
        float p0 = (mv.x != 0.f) ? x0 : 0.f;
        float p1 = (mv.y != 0.f) ? x1 : 0.f;
        mx[(size_t)n * 64 + lane] = f2bf_pk(p0, p1);
        unsigned long long b0 = __ballot(mv.x != 0.f);
        unsigned long long b1 = __ballot(mv.y != 0.f);
        if (lane < 16) {
            unsigned nib0 = (unsigned)(b0 >> (4 * lane)) & 0xFu;
            unsigned nib1 = (unsigned)(b1 >> (4 * lane)) & 0xFu;
            rec[(size_t)n * 32 + lane] = (unsigned char)ilv4(nib0, nib1);
        }
    } else {
        __shared__ int hr[NB], hc[NB];
        for (int i = threadIdx.x; i < NB; i += 256) { hr[i] = 0; hc[i] = 0; }
        __syncthreads();
        int bid = blockIdx.x - PACKB;
        int e0 = bid * ECHUNK, e1 = e0 + ECHUNK;
        for (int e = e0 + threadIdx.x; e < e1; e += 256) {
            atomicAdd(&hr[row[e] >> 8], 1);
            atomicAdd(&hc[col[e] >> 8], 1);
        }
        __syncthreads();
        for (int i = threadIdx.x; i < NB; i += 256) {
            atomicAdd(&crow[i], hr[i]);
            atomicAdd(&ccol[i], hc[i]);
        }
    }
}

// ---- scan both coarse hists -> bases + cursors; rowstart[NN] = NE ----
__global__ __launch_bounds__(256) void cscan_kernel(const int* __restrict__ crow,
                                                    const int* __restrict__ ccol,
                                                    int* __restrict__ crow_base,
                                                    int* __restrict__ ccol_base,
                                                    int* __restrict__ crow_cur,
                                                    int* __restrict__ ccol_cur,
                                                    int* __restrict__ rowstart) {
    __shared__ int ws[4];
    int t = threadIdx.x, lane = t & 63, wid = t >> 6;
    {
        int v = (t < NB) ? crow[t] : 0;
        int incl = v;
        #pragma unroll
        for (int off = 1; off < 64; off <<= 1) { int s = __shfl_up(incl, off); if (lane >= off) incl += s; }
        if (lane == 63) ws[wid] = incl;
        __syncthreads();
        int wbase = 0;
        for (int k = 0; k < wid; k++) wbase += ws[k];
        int ex = wbase + incl - v;
        if (t < NB) { crow_base[t] = ex; crow_cur[t] = ex; }
        if (t == 0) { crow_base[NB] = NE; rowstart[NN] = NE; }
        __syncthreads();
    }
    {
        int v = (t < NB) ? ccol[t] : 0;
        int incl = v;
        #pragma unroll
        for (int off = 1; off < 64; off <<= 1) { int s = __shfl_up(incl, off); if (lane >= off) incl += s; }
        if (lane == 63) ws[wid] = incl;
        __syncthreads();
        int wbase = 0;
        for (int k = 0; k < wid; k++) wbase += ws[k];
        int ex = wbase + incl - v;
        if (t < NB) { ccol_base[t] = ex; ccol_cur[t] = ex; }
        if (t == 0) ccol_base[NB] = NE;
    }
}

// ---- bucket scatter: rrec = (row&255)<<16 | col keyed row>>8; crec = col&255 keyed col>>8 ----
__global__ __launch_bounds__(256) void scatter_kernel(const int* __restrict__ row,
                                                      const int* __restrict__ col,
                                                      int* __restrict__ crow_cur,
                                                      int* __restrict__ ccol_cur,
                                                      unsigned* __restrict__ rrec,
                                                      unsigned char* __restrict__ crec) {
    __shared__ int cntR[NB], cntC[NB], curR[NB], curC[NB];
    for (int i = threadIdx.x; i < NB; i += 256) { cntR[i] = 0; cntC[i] = 0; }
    __syncthreads();
    int e0 = blockIdx.x * ECHUNK, e1 = e0 + ECHUNK;
    for (int e = e0 + threadIdx.x; e < e1; e += 256) {
        atomicAdd(&cntR[row[e] >> 8], 1);
        atomicAdd(&cntC[col[e] >> 8], 1);
    }
    __syncthreads();
    for (int i = threadIdx.x; i < NB; i += 256) {
        curR[i] = atomicAdd(&crow_cur[i], cntR[i]);
        curC[i] = atomicAdd(&ccol_cur[i], cntC[i]);
    }
    __syncthreads();
    for (int e = e0 + threadIdx.x; e < e1; e += 256) {
        int r = row[e], c = col[e];
        int pr = atomicAdd(&curR[r >> 8], 1);
        rrec[pr] = ((unsigned)(r & 255) << 16) | (unsigned)c;
        int pc = atomicAdd(&curC[c >> 8], 1);
        crec[pc] = (unsigned char)(c & 255);
    }
}

// ---- fused fine pass: blocks 0..NB = row sort (rowstart+srcs); NB..2NB = col hist -> dinv into rec ----
__global__ __launch_bounds__(256) void fine_kernel(const unsigned* __restrict__ rrec,
                                                   const unsigned char* __restrict__ crec,
                                                   const int* __restrict__ crow_base,
                                                   const int* __restrict__ ccol_base,
                                                   int* __restrict__ rowstart,
                                                   unsigned short* __restrict__ srcs,
                                                   unsigned char* __restrict__ rec) {
    __shared__ int hist[256];
    __shared__ int ws[4];
    int t = threadIdx.x, lane = t & 63, wid = t >> 6;
    hist[t] = 0;
    __syncthreads();
    if (blockIdx.x < NB) {
        int b = blockIdx.x;
        int s0 = crow_base[b], s1 = crow_base[b + 1];
        for (int j = s0 + t; j < s1; j += 256)
            atomicAdd(&hist[(rrec[j] >> 16) & 255], 1);
        __syncthreads();
        int v = hist[t];
        int incl = v;
        #pragma unroll
        for (int off = 1; off < 64; off <<= 1) { int s = __shfl_up(incl, off); if (lane >= off) incl += s; }
        if (lane == 63) ws[wid] = incl;
        __syncthreads();
        int wbase = 0;
        for (int k = 0; k < wid; k++) wbase += ws[k];
        int ex = wbase + incl - v;
        int node = b * 256 + t;
        if (node < NN) rowstart[node] = s0 + ex;
        hist[t] = ex;
        __syncthreads();
        for (int j = s0 + t; j < s1; j += 256) {
            unsigned r2 = rrec[j];
            int pos = atomicAdd(&hist[(r2 >> 16) & 255], 1);
            srcs[s0 + pos] = (unsigned short)(r2 & 0xFFFFu);
        }
    } else {
        int b = blockIdx.x - NB;
        int s0 = ccol_base[b], s1 = ccol_base[b + 1];
        for (int j = s0 + t; j < s1; j += 256)
            atomicAdd(&hist[crec[j]], 1);
        __syncthreads();
        int node = b * 256 + t;
        if (node < NN) {
            int d = hist[t];
            float dv = (d > 0) ? rsqrtf((float)d) : 0.0f;
            *(float*)(rec + (size_t)node * 32 + 16) = dv;
        }
    }
}

// ---- gather + fused ratio: one wave per dst node, 8 edges in flight, bf16 out ----
__global__ __launch_bounds__(256) void gather_kernel(
        const int* __restrict__ rowstart, const unsigned short* __restrict__ srcs,
        const uint4* __restrict__ mxv, const unsigned char* __restrict__ rec,
        unsigned* __restrict__ rb) {
    int lane = threadIdx.x & 63;
    int r = blockIdx.x * 4 + (threadIdx.x >> 6);
    int l16 = lane & 15, sub = lane >> 4;
    int s0 = rowstart[r], s1 = rowstart[r + 1];
    float dr = *(const float*)(rec + (size_t)r * 32 + 16);
    float num[8] = {0.f,0.f,0.f,0.f,0.f,0.f,0.f,0.f};
    float den[8] = {0.f,0.f,0.f,0.f,0.f,0.f,0.f,0.f};
    float S = 0.f;

    for (int j = s0; j < s1; j += 8) {
        // group A: edges j+sub
        {
            int jj = j + sub;
            int cl = (jj < s1) ? jj : (s1 - 1);
            int c = srcs[cl];
            float w = (jj < s1) ? *(const float*)(rec + (size_t)c * 32 + 16) : 0.f;
            uint4 u = mxv[(size_t)c * 16 + l16];
            unsigned mb = rec[(size_t)c * 32 + l16];
            float f[8];
            f[0] = __uint_as_float(u.x << 16); f[1] = __uint_as_float(u.x & 0xffff0000u);
            f[2] = __uint_as_float(u.y << 16); f[3] = __uint_as_float(u.y & 0xffff0000u);
            f[4] = __uint_as_float(u.z << 16); f[5] = __uint_as_float(u.z & 0xffff0000u);
            f[6] = __uint_as_float(u.w << 16); f[7] = __uint_as_float(u.w & 0xffff0000u);
            S += w;
            #pragma unroll
            for (int q = 0; q < 8; q++) {
                num[q] += w * f[q];
                den[q] += ((mb >> q) & 1u) ? w : 0.f;
            }
        }
        // group B: edges j+4+sub
        {
            int jj = j + 4 + sub;
            int cl = (jj < s1) ? jj : (s1 - 1);
            int c = srcs[cl];
            float w = (jj < s1) ? *(const float*)(rec + (size_t)c * 32 + 16) : 0.f;
            uint4 u = mxv[(size_t)c * 16 + l16];
            unsigned mb = rec[(size_t)c * 32 + l16];
            float f[8];
            f[0] = __uint_as_float(u.x << 16); f[1] = __uint_as_float(u.x & 0xffff0000u);
            f[2] = __uint_as_float(u.y << 16); f[3] = __uint_as_float(u.y & 0xffff0000u);
            f[4] = __uint_as_float(u.z << 16); f[5] = __uint_as_float(u.z & 0xffff0000u);
            f[6] = __uint_as_float(u.w << 16); f[7] = __uint_as_float(u.w & 0xffff0000u);
            S += w;
            #pragma unroll
            for (int q = 0; q < 8; q++) {
                num[q] += w * f[q];
                den[q] += ((mb >> q) & 1u) ? w : 0.f;
            }
        }
    }

    #pragma unroll
    for (int q = 0; q < 8; q++) {
        num[q] += __shfl_xor(num[q], 16); num[q] += __shfl_xor(num[q], 32);
        den[q] += __shfl_xor(den[q], 16); den[q] += __shfl_xor(den[q], 32);
    }
    S += __shfl_xor(S, 16); S += __shfl_xor(S, 32);

    if (sub == 0) {
        float kf = dr * S;
        float o[8];
        #pragma unroll
        for (int q = 0; q < 8; q++)
            o[q] = (den[q] != 0.f) ? kf * num[q] / den[q] : 0.f;
        uint4 pk;
        pk.x = f2bf_pk(o[0], o[1]);
        pk.y = f2bf_pk(o[2], o[3]);
        pk.z = f2bf_pk(o[4], o[5]);
        pk.w = f2bf_pk(o[6], o[7]);
        ((uint4*)rb)[(size_t)r * 16 + l16] = pk;
    }
}

// ---- out = Abf16 @ W^T + b via MFMA (A read directly as bf16) ----
__global__ __launch_bounds__(256) void gemm_kernel(const unsigned short* __restrict__ Ab,
                                                   const float* __restrict__ W,
                                                   const float* __restrict__ bias,
                                                   float* __restrict__ out) {
    __shared__ unsigned short Wlds[F * WPAD];
    int tid = threadIdx.x;

    for (int i = tid * 4; i < F * F; i += 256 * 4) {
        int c = i >> 7, k = i & 127;
        float4 v = *(const float4*)(W + i);
        unsigned lo = f2bf_pk(v.x, v.y);
        unsigned hi = f2bf_pk(v.z, v.w);
        *(uint2*)&Wlds[c * WPAD + k] = make_uint2(lo, hi);
    }
    __syncthreads();

    int lane = tid & 63, wid = tid >> 6;
    int m = lane & 15, quad = lane >> 4;
    int arow = blockIdx.x * 64 + wid * 16 + m;
    int lrow = (arow < NN) ? arow : (NN - 1);
    const unsigned short* Arow = Ab + (size_t)lrow * F + quad * 8;

    floatx4 acc[8];
    #pragma unroll
    for (int nt = 0; nt < 8; nt++) acc[nt] = (floatx4)(0.f);

    #pragma unroll
    for (int step = 0; step < 4; step++) {
        short8 af = *(const short8*)(Arow + step * 32);
        #pragma unroll
        for (int nt = 0; nt < 8; nt++) {
            short8 bf = *(const short8*)&Wlds[(nt * 16 + m) * WPAD + step * 32 + quad * 8];
            acc[nt] = __builtin_amdgcn_mfma_f32_16x16x32_bf16(af, bf, acc[nt], 0, 0, 0);
        }
    }

    int orow0 = blockIdx.x * 64 + wid * 16 + quad * 4;
    #pragma unroll
    for (int nt = 0; nt < 8; nt++) {
        float bv = bias[nt * 16 + m];
        #pragma unroll
        for (int p = 0; p < 4; p++) {
            int gr = orow0 + p;
            if (gr < NN) out[(size_t)gr * F + nt * 16 + m] = acc[nt][p] + bv;
        }
    }
}

extern "C" void kernel_launch(void* const* d_in, const int* in_sizes, int n_in,
                              void* d_out, int out_size, void* d_ws, size_t ws_size,
                              hipStream_t stream) {
    const float* x    = (const float*)d_in[0];
    const float* mask = (const float*)d_in[1];
    const int*   ei   = (const int*)d_in[2];
    const float* W    = (const float*)d_in[3];
    const float* b    = (const float*)d_in[4];
    float* out = (float*)d_out;

    const int* row = ei;
    const int* col = ei + NE;

    // ws layout (16 B aligned segments first)
    unsigned*       mx        = (unsigned*)d_ws;                          // NN*64 u32 (12.8 MB)
    unsigned*       rb        = mx + (size_t)NN * 64;                     // NN*64 u32 bf16 ratio (12.8 MB)
    unsigned char*  rec       = (unsigned char*)(rb + (size_t)NN * 64);   // NN*32 B {bits16, dinv}
    unsigned*       rrec      = (unsigned*)(rec + (size_t)NN * 32);       // NE u32
    unsigned short* srcs      = (unsigned short*)(rrec + NE);             // NE u16
    unsigned char*  crec      = (unsigned char*)(srcs + NE);              // NE u8
    int*            crow      = (int*)(crec + NE);                        // NB
    int*            ccol      = crow + NB;                                // NB
    int*            crow_base = ccol + NB;                                // NB+1
    int*            ccol_base = crow_base + NB + 1;                       // NB+1
    int*            crow_cur  = ccol_base + NB + 1;                       // NB
    int*            ccol_cur  = crow_cur + NB;                            // NB
    int*            rowstart  = ccol_cur + NB;                            // NN+1

    hipMemsetAsync(crow, 0, 2 * NB * sizeof(int), stream);

    pc_kernel<<<PACKB + CHB, 256, 0, stream>>>(x, mask, row, col, mx, rec, crow, ccol);
    cscan_kernel<<<1, 256, 0, stream>>>(crow, ccol, crow_base, ccol_base,
                                        crow_cur, ccol_cur, rowstart);
    scatter_kernel<<<CHB, 256, 0, stream>>>(row, col, crow_cur, ccol_cur, rrec, crec);
    fine_kernel<<<2 * NB, 256, 0, stream>>>(rrec, crec, crow_base, ccol_base,
                                            rowstart, srcs, rec);
    gather_kernel<<<NN / 4, 256, 0, stream>>>(rowstart, srcs,
                                              (const uint4*)mx, rec, rb);
    gemm_kernel<<<(NN + 63) / 64, 256, 0, stream>>>((const unsigned short*)rb, W, b, out);
}